// Round 8
// baseline (72.783 us; speedup 1.0000x reference)
//
#include <hip/hip_runtime.h>
#include <hip/hip_bf16.h>

// SimpleGATLayer fused kernel set for MI355X (gfx950).
// B=8, N=2048, F=U=128 (hard-coded from reference setup).
//
//  k_wt     : W(f,u) f32 -> WT(u,f) bf16          (tiny)
//  k_h_pack : blocks [0,1024): pack A (int32 0/1) -> 1-bit mask (4.2 MB),
//             shuffle-free, 8 independent int4 loads in flight per lane.
//             blocks [1024,1280): H = X@W via MFMA -> HT(b,u,n) bf16, s, t.
//  k_attn   : fused masked softmax(leaky(s_i+t_j)) @ H, relu, f32 out.
//             Round 8: T4 counted-vmcnt pipeline — raw s_barrier pairs with
//             s_waitcnt vmcnt(5) keep next-tile gload_lds staging in flight
//             across the barrier (replaces the full vmcnt(0) drain that
//             __syncthreads emits every tile).

#define NEG_INF -1.0e9f

typedef __bf16 bf16x8 __attribute__((ext_vector_type(8)));
typedef unsigned short ushort8 __attribute__((ext_vector_type(8)));
typedef float f32x4 __attribute__((ext_vector_type(4)));

__device__ __forceinline__ unsigned short f2b(float x) {
    // f32 -> bf16 round-to-nearest-even
    unsigned u = __builtin_bit_cast(unsigned, x);
    u += 0x7fffu + ((u >> 16) & 1u);
    return (unsigned short)(u >> 16);
}

__device__ __forceinline__ void gload_lds16(const void* g, void* l) {
    __builtin_amdgcn_global_load_lds(
        (const __attribute__((address_space(1))) void*)g,
        (__attribute__((address_space(3))) void*)l, 16, 0, 0);
}

// ---------------- K0: W transpose+convert ----------------
__global__ __launch_bounds__(256) void k_wt(const float* __restrict__ W,
                                            unsigned short* __restrict__ WT) {
    int tid = blockIdx.x * 256 + threadIdx.x;   // 16384 elements
    int u = tid >> 7, f = tid & 127;
    WT[tid] = f2b(W[f * 128 + u]);              // WT[u][f] = W[f][u]
}

// ---------------- K1: A -> bitmask  ||  H = X@W (+ s,t, HT) ----------------
// grid = 1280 blocks x 256 thr.
// blocks [0,1024):  pack path — wave handles 4 rows; lane l builds the u32
//                   word for columns [32l,32l+32) via 8 independent int4
//                   loads (128 B contiguous per lane) -> full MLP, no
//                   cross-lane ops, coalesced 256 B/wave stores.
// blocks [1024,1280): H path — each wave computes 16 rows x 128 u.
__global__ __launch_bounds__(256) void k_h_pack(const float* __restrict__ X,
                                                const unsigned short* __restrict__ WT,
                                                const float* __restrict__ a,
                                                const int* __restrict__ A,
                                                unsigned short* __restrict__ HT,
                                                float* __restrict__ sbuf,
                                                float* __restrict__ tbuf,
                                                unsigned int* __restrict__ Abits) {
    const int tid  = threadIdx.x;
    const int w    = tid >> 6;
    const int lane = tid & 63;

    if (blockIdx.x < 1024) {
        // ---- pack path: A (33.5M int32) -> 4.2 MB bitmask ----
        const int wid = blockIdx.x * 4 + w;              // 0..4095
#pragma unroll 2
        for (int rr = 0; rr < 4; ++rr) {
            const int row = wid * 4 + rr;                // 0..16383
            const int* Ap = A + (size_t)row * 2048 + lane * 32;
            unsigned int word = 0;
#pragma unroll
            for (int kk = 0; kk < 8; ++kk) {
                int4 v = *(const int4*)(Ap + kk * 4);
                word |= (v.x > 0 ? 1u : 0u) << (kk * 4 + 0);
                word |= (v.y > 0 ? 1u : 0u) << (kk * 4 + 1);
                word |= (v.z > 0 ? 1u : 0u) << (kk * 4 + 2);
                word |= (v.w > 0 ? 1u : 0u) << (kk * 4 + 3);
            }
            Abits[(size_t)row * 64 + lane] = word;
        }
        return;
    }

    // ---- H path ----
    const int r    = lane & 15;     // MFMA row/col index
    const int cg   = lane >> 4;     // k-group 0..3
    const int row0 = (blockIdx.x - 1024) * 64 + w * 16; // flattened row
    const int b    = row0 >> 11;
    const int n0   = row0 & 2047;
    const int arow = row0 + r;

    f32x4 acc[8] = {};

#pragma unroll
    for (int k0 = 0; k0 < 128; k0 += 32) {
        const float* xp = X + (size_t)arow * 128 + k0 + cg * 8;
        ushort8 xa;
#pragma unroll
        for (int j = 0; j < 8; j++) xa[j] = f2b(xp[j]);
        bf16x8 av = __builtin_bit_cast(bf16x8, xa);
#pragma unroll
        for (int ut = 0; ut < 8; ut++) {
            ushort8 wb = *(const ushort8*)(WT + (size_t)(ut * 16 + r) * 128 + k0 + cg * 8);
            acc[ut] = __builtin_amdgcn_mfma_f32_16x16x32_bf16(
                av, __builtin_bit_cast(bf16x8, wb), acc[ut], 0, 0, 0);
        }
    }

    // D layout: lane holds H[row0 + cg*4 + reg][ut*16 + r]
    float sp[4] = {0.f, 0.f, 0.f, 0.f};
    float tp[4] = {0.f, 0.f, 0.f, 0.f};
#pragma unroll
    for (int ut = 0; ut < 8; ut++) {
        int u = ut * 16 + r;
        float as = a[u];
        float ad = a[128 + u];
#pragma unroll
        for (int reg = 0; reg < 4; reg++) {
            float h = acc[ut][reg];
            int nrow = n0 + cg * 4 + reg;
            HT[((size_t)b * 128 + u) * 2048 + nrow] = f2b(h);
            sp[reg] += h * as;
            tp[reg] += h * ad;
        }
    }
#pragma unroll
    for (int msk = 1; msk < 16; msk <<= 1) {
#pragma unroll
        for (int reg = 0; reg < 4; reg++) {
            sp[reg] += __shfl_xor(sp[reg], msk);
            tp[reg] += __shfl_xor(tp[reg], msk);
        }
    }
    if (r == 0) {
#pragma unroll
        for (int reg = 0; reg < 4; reg++) {
            int row = row0 + cg * 4 + reg;
            sbuf[row] = sp[reg];
            tbuf[row] = tp[reg];
        }
    }
}

// ---------------- K2: fused masked-softmax attention @ H ----------------
// grid = 512 blocks (2/CU), block = 512 thr (8 waves).
// Block: 32 i-rows x 128 u of batch b = bid&7 (b-per-XCD locality).
// Wave w: i-subtile g=w&1 (16 rows), j-quarter jq=w>>1 (512 j, 16 tiles of 32).
// t staged once into LDS; A via 1-bit mask (L1-resident, prefetched 1 ahead);
// HT j-tiles staged via global_load_lds (dbuf, XOR-swizzled).
// Pipeline per tile (T3/T4):
//   issue stage(k+1) + mask(k+1) -> compute P_k -> s_waitcnt vmcnt(5)
//   [tile-k loads done, tile-k+1's 4 + mask stay in flight] -> s_barrier ->
//   ds_read+MFMA tile k -> s_barrier (WAR guard on buffer flip).
__global__ __launch_bounds__(512, 4) void k_attn(const unsigned int* __restrict__ Abits,
                                                 const unsigned short* __restrict__ HT,
                                                 const float* __restrict__ sbuf,
                                                 const float* __restrict__ tbuf,
                                                 float* __restrict__ out) {
    __shared__ char smem[65536];        // stage: [jq][p][8KB]; reused for combine
    __shared__ float tS[2048];          // t row for this batch (8 KB)
    __shared__ float dSm[4][2][16];

    const int tid  = threadIdx.x;
    const int w    = tid >> 6;          // 0..7
    const int lane = tid & 63;
    const int r    = lane & 15;
    const int cg   = lane >> 4;
    const int g    = w & 1;             // i-subtile (16 rows)
    const int jq   = w >> 1;            // j-quarter (512 j)
    const int bid  = blockIdx.x;
    const int b    = bid & 7;           // batch pinned per XCD
    const int it   = bid >> 3;          // 0..63 i-tile
    const int i0   = it * 32;
    const int rot  = it & 15;           // per-block j-tile rotation

    const int irow = i0 + g * 16 + r;
    const float s_r = sbuf[b * 2048 + irow];
    // mask words for this row's quarter: 16 u32 (32 j-bits each)
    const unsigned int* Mrow = Abits + ((size_t)(b * 2048 + irow)) * 64 + jq * 16;
    const unsigned short* Hb = HT + ((size_t)b * 128) * 2048 + jq * 512;

    // staging geometry: wave stages 64 u-rows (4 instrs x 16 rows).
    // LDS tile = 128 rows x 64B (4 chunks of 16B); chunk hash both sides.
    const int srow = (lane >> 2);
    const int csrc = (lane & 3) ^ ((lane >> 2) & 3) ^ ((lane >> 4) & 3);
    char* const qbase = smem + jq * 16384;            // this quarter's 2 buffers
    const unsigned short* src0 = Hb + (size_t)(g * 64 + srow) * 2048 + csrc * 8;
    const int rsl = ((r & 3) ^ ((r >> 2) & 3));       // read-side hash base

    f32x4 acc[8] = {};
    float den = 0.f;

    // ---- stage t row once (512 thr x float4 = 2048 f32) ----
    *(float4*)(tS + tid * 4) = *(const float4*)(tbuf + b * 2048 + tid * 4);

    // ---- prologue: stage HT tile 'rot' + prefetch mask word ----
    unsigned int mw = Mrow[rot];
    {
        const int j0 = rot * 32;
#pragma unroll
        for (int i = 0; i < 4; i++)
            gload_lds16(src0 + (size_t)i * 16 * 2048 + j0,
                        qbase + (g * 4 + i) * 1024);
    }
    __syncthreads();   // full drain once: t + stage0 visible, vm queue empty

    for (int k = 0; k < 16; ++k) {
        const int p = k & 1;
        unsigned int mwn = 0;
        if (k < 15) {
            const int kn = (k + 1 + rot) & 15;
            char* dst = qbase + (p ^ 1) * 8192;
#pragma unroll
            for (int i = 0; i < 4; i++)
                gload_lds16(src0 + (size_t)i * 16 * 2048 + kn * 32,
                            dst + (g * 4 + i) * 1024);
            mwn = Mrow[kn];
        }

        // t fragment from LDS; P from mask bits + fixed-scale exp
        const float* tq = tS + jq * 512 + ((k + rot) & 15) * 32 + cg * 8;
        float4 t0 = *(const float4*)(tq);
        float4 t1 = *(const float4*)(tq + 4);
        float tv[8] = {t0.x, t0.y, t0.z, t0.w, t1.x, t1.y, t1.z, t1.w};
        const unsigned int sh = mw >> (cg * 8);
        bf16x8 pa;
#pragma unroll
        for (int jj = 0; jj < 8; jj++) {
            float x = s_r + tv[jj];
            float e = fmaxf(x, 0.2f * x);          // leaky_relu
            float pp = __expf(e - 16.0f);
            pp = ((sh >> jj) & 1u) ? pp : 0.f;     // mask
            den += pp;
            pa[jj] = (__bf16)pp;
        }

        // T4: wait only for tile k's staging (tile k+1's 4 loads + its mask
        // prefetch remain in flight across the barrier).
        if (k < 15) asm volatile("s_waitcnt vmcnt(5)" ::: "memory");
        else        asm volatile("s_waitcnt vmcnt(0)" ::: "memory");
        __builtin_amdgcn_s_barrier();
        __builtin_amdgcn_sched_barrier(0);   // rule #18: no ds_read hoisting

        // B fragments from staged LDS tile (hashed chunk slots) + MFMA
        const char* buf = qbase + p * 8192;
#pragma unroll
        for (int ut = 0; ut < 8; ut++) {
            ushort8 hb = *(const ushort8*)(buf + (ut * 16 + r) * 64 +
                                           ((cg ^ rsl) * 16));
            acc[ut] = __builtin_amdgcn_mfma_f32_16x16x32_bf16(
                pa, __builtin_bit_cast(bf16x8, hb), acc[ut], 0, 0, 0);
        }

        mw = mwn;
        __builtin_amdgcn_s_barrier();        // WAR guard: buffer p is about to
        __builtin_amdgcn_sched_barrier(0);   // be overwritten next iteration
    }

    // per-wave denominator per row (sum over the 4 cg k-groups)
    den += __shfl_xor(den, 16);
    den += __shfl_xor(den, 32);

    // ---- combine the 4 j-quarters (reuse smem; padded stride 132 f32) ----
    float* accS = (float*)smem;
    if (cg == 0) dSm[jq][g][r] = den;     // lane r holds row r's partial
    if (jq != 0) {
        const int rowIdx = ((jq - 1) * 2 + g) * 16 + cg * 4;
#pragma unroll
        for (int ut = 0; ut < 8; ut++)
#pragma unroll
            for (int reg = 0; reg < 4; reg++)
                accS[(rowIdx + reg) * 132 + ut * 16 + r] = acc[ut][reg];
    }
    __syncthreads();
    if (jq == 0) {
        float dinv[4];
#pragma unroll
        for (int reg = 0; reg < 4; reg++) {
            const int row = cg * 4 + reg;
            dinv[reg] = 1.0f / (dSm[0][g][row] + dSm[1][g][row] +
                                dSm[2][g][row] + dSm[3][g][row]);
        }
#pragma unroll
        for (int ut = 0; ut < 8; ut++) {
#pragma unroll
            for (int reg = 0; reg < 4; reg++) {
                const int lrow = cg * 4 + reg;
                float num = acc[ut][reg]
                          + accS[((0 * 2 + g) * 16 + lrow) * 132 + ut * 16 + r]
                          + accS[((1 * 2 + g) * 16 + lrow) * 132 + ut * 16 + r]
                          + accS[((2 * 2 + g) * 16 + lrow) * 132 + ut * 16 + r];
                float o = fmaxf(num * dinv[reg], 0.f);
                out[((size_t)(b * 2048 + i0 + g * 16 + lrow)) * 128 +
                    ut * 16 + r] = o;
            }
        }
    }
}

extern "C" void kernel_launch(void* const* d_in, const int* in_sizes, int n_in,
                              void* d_out, int out_size, void* d_ws, size_t ws_size,
                              hipStream_t stream) {
    const float* X = (const float*)d_in[0];   // (8,2048,128) f32
    const int*   A = (const int*)d_in[1];     // (8,2048,2048) i32
    const float* W = (const float*)d_in[2];   // (128,128) f32
    const float* a = (const float*)d_in[3];   // (256,1) f32
    float* out = (float*)d_out;               // (8,2048,128) f32

    char* ws = (char*)d_ws;
    unsigned short* WT  = (unsigned short*)(ws);                  // 32 KB
    float*          sb  = (float*)(ws + 32768);                   // 64 KB
    float*          tb  = (float*)(ws + 98304);                   // 64 KB
    unsigned short* HT  = (unsigned short*)(ws + 163840);         // 4 MB
    unsigned int*   Ab  = (unsigned int*)(ws + 163840 + 4194304); // 4.2 MB

    k_wt<<<dim3(64), dim3(256), 0, stream>>>(W, WT);
    k_h_pack<<<dim3(1280), dim3(256), 0, stream>>>(X, WT, a, A, HT, sb, tb, Ab);
    k_attn<<<dim3(512), dim3(512), 0, stream>>>(Ab, HT, sb, tb, out);
}

// Round 9
// 65.379 us; speedup vs baseline: 1.1132x; 1.1132x over previous
//
#include <hip/hip_runtime.h>
#include <hip/hip_bf16.h>

// SimpleGATLayer fused kernel set for MI355X (gfx950).
// B=8, N=2048, F=U=128 (hard-coded from reference setup).
//
//  k_wt   : W(f,u) f32 -> WT(u,f) bf16          (tiny)
//  k_h    : H = X@W via MFMA -> HT(b,u,n) bf16, s(b,n), t(b,n) f32
//  k_attn : fused masked softmax(leaky(s_i+t_j)) @ H, relu, f32 out.
//           Round 9: per-block A self-pack prologue (256 KB slab -> 8 KB
//           LDS bits -> 16 mask words in registers, loop fully unrolled).
//           Eliminates the serial pack kernel + Abits round-trip; the
//           A-stream of co-resident blocks overlaps other blocks' loops.
//           Loop body = R7 structure (plain __syncthreads; R8's counted
//           vmcnt reverted — its in-flight loads are short-latency L2).

#define NEG_INF -1.0e9f

typedef __bf16 bf16x8 __attribute__((ext_vector_type(8)));
typedef unsigned short ushort8 __attribute__((ext_vector_type(8)));
typedef float f32x4 __attribute__((ext_vector_type(4)));

__device__ __forceinline__ unsigned short f2b(float x) {
    // f32 -> bf16 round-to-nearest-even
    unsigned u = __builtin_bit_cast(unsigned, x);
    u += 0x7fffu + ((u >> 16) & 1u);
    return (unsigned short)(u >> 16);
}

__device__ __forceinline__ void gload_lds16(const void* g, void* l) {
    __builtin_amdgcn_global_load_lds(
        (const __attribute__((address_space(1))) void*)g,
        (__attribute__((address_space(3))) void*)l, 16, 0, 0);
}

// ---------------- K0: W transpose+convert ----------------
__global__ __launch_bounds__(256) void k_wt(const float* __restrict__ W,
                                            unsigned short* __restrict__ WT) {
    int tid = blockIdx.x * 256 + threadIdx.x;   // 16384 elements
    int u = tid >> 7, f = tid & 127;
    WT[tid] = f2b(W[f * 128 + u]);              // WT[u][f] = W[f][u]
}

// ---------------- K1: H = X@W, plus s,t and HT ----------------
// grid = 256 blocks x 256 thr; each wave computes 16 rows x 128 u.
__global__ __launch_bounds__(256) void k_h(const float* __restrict__ X,
                                           const unsigned short* __restrict__ WT,
                                           const float* __restrict__ a,
                                           unsigned short* __restrict__ HT,
                                           float* __restrict__ sbuf,
                                           float* __restrict__ tbuf) {
    const int tid  = threadIdx.x;
    const int w    = tid >> 6;
    const int lane = tid & 63;
    const int r    = lane & 15;     // MFMA row/col index
    const int cg   = lane >> 4;     // k-group 0..3
    const int row0 = blockIdx.x * 64 + w * 16;  // flattened (b*2048+n) row
    const int b    = row0 >> 11;
    const int n0   = row0 & 2047;
    const int arow = row0 + r;

    f32x4 acc[8] = {};

#pragma unroll
    for (int k0 = 0; k0 < 128; k0 += 32) {
        const float* xp = X + (size_t)arow * 128 + k0 + cg * 8;
        ushort8 xa;
#pragma unroll
        for (int j = 0; j < 8; j++) xa[j] = f2b(xp[j]);
        bf16x8 av = __builtin_bit_cast(bf16x8, xa);
#pragma unroll
        for (int ut = 0; ut < 8; ut++) {
            ushort8 wb = *(const ushort8*)(WT + (size_t)(ut * 16 + r) * 128 + k0 + cg * 8);
            acc[ut] = __builtin_amdgcn_mfma_f32_16x16x32_bf16(
                av, __builtin_bit_cast(bf16x8, wb), acc[ut], 0, 0, 0);
        }
    }

    // D layout: lane holds H[row0 + cg*4 + reg][ut*16 + r]
    float sp[4] = {0.f, 0.f, 0.f, 0.f};
    float tp[4] = {0.f, 0.f, 0.f, 0.f};
#pragma unroll
    for (int ut = 0; ut < 8; ut++) {
        int u = ut * 16 + r;
        float as = a[u];
        float ad = a[128 + u];
#pragma unroll
        for (int reg = 0; reg < 4; reg++) {
            float h = acc[ut][reg];
            int nrow = n0 + cg * 4 + reg;
            HT[((size_t)b * 128 + u) * 2048 + nrow] = f2b(h);
            sp[reg] += h * as;
            tp[reg] += h * ad;
        }
    }
#pragma unroll
    for (int msk = 1; msk < 16; msk <<= 1) {
#pragma unroll
        for (int reg = 0; reg < 4; reg++) {
            sp[reg] += __shfl_xor(sp[reg], msk);
            tp[reg] += __shfl_xor(tp[reg], msk);
        }
    }
    if (r == 0) {
#pragma unroll
        for (int reg = 0; reg < 4; reg++) {
            int row = row0 + cg * 4 + reg;
            sbuf[row] = sp[reg];
            tbuf[row] = tp[reg];
        }
    }
}

// ---------------- K2: fused masked-softmax attention @ H ----------------
// grid = 512 blocks (2/CU), block = 512 thr (8 waves).
// Block: 32 i-rows x 128 u of batch b = bid&7 (b-per-XCD locality).
// Wave w: i-subtile g=w&1 (16 rows), j-quarter jq=w>>1 (512 j, 16 tiles of 32).
// Prologue: (1) self-pack this block's A slab (32x2048 int32 -> 32x64 u32
// bits in LDS, R7 pack pattern), (2) stage t row, (3) each lane pulls its
// 16 mask words into registers (bits region then released to the stage
// buffers), (4) stage HT tile 0. Loop (fully unrolled, static mask regs):
// gload_lds dbuf of HT tiles + fixed-scale softmax p=exp(e-16) + MFMA.
__global__ __launch_bounds__(512, 4) void k_attn(const int* __restrict__ A,
                                                 const unsigned short* __restrict__ HT,
                                                 const float* __restrict__ sbuf,
                                                 const float* __restrict__ tbuf,
                                                 float* __restrict__ out) {
    __shared__ char smem[65536];        // bits (prologue) -> stage -> combine
    __shared__ float tS[2048];          // t row for this batch (8 KB)
    __shared__ float dSm[4][2][16];

    const int tid  = threadIdx.x;
    const int w    = tid >> 6;          // 0..7
    const int lane = tid & 63;
    const int r    = lane & 15;
    const int cg   = lane >> 4;
    const int g    = w & 1;             // i-subtile (16 rows)
    const int jq   = w >> 1;            // j-quarter (512 j)
    const int bid  = blockIdx.x;
    const int b    = bid & 7;           // batch pinned per XCD
    const int it   = bid >> 3;          // 0..63 i-tile
    const int i0   = it * 32;
    const int rot  = it & 15;           // per-block j-tile rotation

    const int irow = i0 + g * 16 + r;
    const float s_r = sbuf[b * 2048 + irow];
    const unsigned short* Hb = HT + ((size_t)b * 128) * 2048 + jq * 512;

    // ---- Phase 1: self-pack A slab into LDS bits (stride-65 u32 rows) ----
    // Wave w packs rows i0+w*4 .. +4; lane l builds word l (j in [32l,32l+32)).
    unsigned int* bitsS = (unsigned int*)smem;   // 32 x 65 u32 = 8320 B
    {
        const int* Abase = A + ((size_t)(b * 2048 + i0 + w * 4)) * 2048;
#pragma unroll
        for (int rr = 0; rr < 4; ++rr) {
            const int* Ap = Abase + rr * 2048 + lane * 32;
            unsigned int word = 0;
#pragma unroll
            for (int kk = 0; kk < 8; ++kk) {
                int4 v = *(const int4*)(Ap + kk * 4);
                word |= (v.x > 0 ? 1u : 0u) << (kk * 4 + 0);
                word |= (v.y > 0 ? 1u : 0u) << (kk * 4 + 1);
                word |= (v.z > 0 ? 1u : 0u) << (kk * 4 + 2);
                word |= (v.w > 0 ? 1u : 0u) << (kk * 4 + 3);
            }
            bitsS[(w * 4 + rr) * 65 + lane] = word;
        }
    }
    // ---- stage t row once (512 thr x float4 = 2048 f32) ----
    *(float4*)(tS + tid * 4) = *(const float4*)(tbuf + b * 2048 + tid * 4);
    __syncthreads();

    // ---- Phase 2: pull my 16 mask words into registers (rotated order) ----
    unsigned int wordsR[16];
#pragma unroll
    for (int k = 0; k < 16; ++k)
        wordsR[k] = bitsS[(g * 16 + r) * 65 + jq * 16 + ((k + rot) & 15)];
    __syncthreads();   // bits region dead; smem becomes the stage buffers

    // staging geometry: wave stages 64 u-rows (4 instrs x 16 rows).
    // LDS tile = 128 rows x 64B (4 chunks of 16B); chunk hash both sides.
    const int srow = (lane >> 2);
    const int csrc = (lane & 3) ^ ((lane >> 2) & 3) ^ ((lane >> 4) & 3);
    char* const qbase = smem + jq * 16384;            // this quarter's 2 buffers
    const unsigned short* src0 = Hb + (size_t)(g * 64 + srow) * 2048 + csrc * 8;
    const int rsl = ((r & 3) ^ ((r >> 2) & 3));       // read-side hash base

    f32x4 acc[8] = {};
    float den = 0.f;

    // ---- Phase 3: prologue HT stage of tile 'rot' ----
    {
        const int j0 = rot * 32;
#pragma unroll
        for (int i = 0; i < 4; i++)
            gload_lds16(src0 + (size_t)i * 16 * 2048 + j0,
                        qbase + (g * 4 + i) * 1024);
    }
    __syncthreads();   // stage 0 visible

    // ---- Phase 4: main loop (fully unrolled -> wordsR static) ----
#pragma unroll
    for (int k = 0; k < 16; ++k) {
        const int p = k & 1;
        if (k < 15) {
            const int kn = (k + 1 + rot) & 15;
            char* dst = qbase + (p ^ 1) * 8192;
#pragma unroll
            for (int i = 0; i < 4; i++)
                gload_lds16(src0 + (size_t)i * 16 * 2048 + kn * 32,
                            dst + (g * 4 + i) * 1024);
        }

        // t fragment from LDS; P from mask bits + fixed-scale exp
        const float* tq = tS + jq * 512 + ((k + rot) & 15) * 32 + cg * 8;
        float4 t0 = *(const float4*)(tq);
        float4 t1 = *(const float4*)(tq + 4);
        float tv[8] = {t0.x, t0.y, t0.z, t0.w, t1.x, t1.y, t1.z, t1.w};
        const unsigned int sh = wordsR[k] >> (cg * 8);
        bf16x8 pa;
#pragma unroll
        for (int jj = 0; jj < 8; jj++) {
            float x = s_r + tv[jj];
            float e = fmaxf(x, 0.2f * x);          // leaky_relu
            float pp = __expf(e - 16.0f);
            pp = ((sh >> jj) & 1u) ? pp : 0.f;     // mask
            den += pp;
            pa[jj] = (__bf16)pp;
        }

        // B fragments from staged LDS tile (hashed chunk slots) + MFMA
        const char* buf = qbase + p * 8192;
#pragma unroll
        for (int ut = 0; ut < 8; ut++) {
            ushort8 hb = *(const ushort8*)(buf + (ut * 16 + r) * 64 +
                                           ((cg ^ rsl) * 16));
            acc[ut] = __builtin_amdgcn_mfma_f32_16x16x32_bf16(
                pa, __builtin_bit_cast(bf16x8, hb), acc[ut], 0, 0, 0);
        }

        __syncthreads();   // drain stage(k+1) writes, protect buffer flip
    }

    // per-wave denominator per row (sum over the 4 cg k-groups)
    den += __shfl_xor(den, 16);
    den += __shfl_xor(den, 32);

    // ---- combine the 4 j-quarters (reuse smem; padded stride 132 f32) ----
    float* accS = (float*)smem;
    if (cg == 0) dSm[jq][g][r] = den;     // lane r holds row r's partial
    if (jq != 0) {
        const int rowIdx = ((jq - 1) * 2 + g) * 16 + cg * 4;
#pragma unroll
        for (int ut = 0; ut < 8; ut++)
#pragma unroll
            for (int reg = 0; reg < 4; reg++)
                accS[(rowIdx + reg) * 132 + ut * 16 + r] = acc[ut][reg];
    }
    __syncthreads();
    if (jq == 0) {
        float dinv[4];
#pragma unroll
        for (int reg = 0; reg < 4; reg++) {
            const int row = cg * 4 + reg;
            dinv[reg] = 1.0f / (dSm[0][g][row] + dSm[1][g][row] +
                                dSm[2][g][row] + dSm[3][g][row]);
        }
#pragma unroll
        for (int ut = 0; ut < 8; ut++) {
#pragma unroll
            for (int reg = 0; reg < 4; reg++) {
                const int lrow = cg * 4 + reg;
                float num = acc[ut][reg]
                          + accS[((0 * 2 + g) * 16 + lrow) * 132 + ut * 16 + r]
                          + accS[((1 * 2 + g) * 16 + lrow) * 132 + ut * 16 + r]
                          + accS[((2 * 2 + g) * 16 + lrow) * 132 + ut * 16 + r];
                float o = fmaxf(num * dinv[reg], 0.f);
                out[((size_t)(b * 2048 + i0 + g * 16 + lrow)) * 128 +
                    ut * 16 + r] = o;
            }
        }
    }
}

extern "C" void kernel_launch(void* const* d_in, const int* in_sizes, int n_in,
                              void* d_out, int out_size, void* d_ws, size_t ws_size,
                              hipStream_t stream) {
    const float* X = (const float*)d_in[0];   // (8,2048,128) f32
    const int*   A = (const int*)d_in[1];     // (8,2048,2048) i32
    const float* W = (const float*)d_in[2];   // (128,128) f32
    const float* a = (const float*)d_in[3];   // (256,1) f32
    float* out = (float*)d_out;               // (8,2048,128) f32

    char* ws = (char*)d_ws;
    unsigned short* WT  = (unsigned short*)(ws);                  // 32 KB
    float*          sb  = (float*)(ws + 32768);                   // 64 KB
    float*          tb  = (float*)(ws + 98304);                   // 64 KB
    unsigned short* HT  = (unsigned short*)(ws + 163840);         // 4 MB

    k_wt<<<dim3(64), dim3(256), 0, stream>>>(W, WT);
    k_h<<<dim3(256), dim3(256), 0, stream>>>(X, WT, a, HT, sb, tb);
    k_attn<<<dim3(512), dim3(512), 0, stream>>>(A, HT, sb, tb, out);
}

// Round 10
// 59.641 us; speedup vs baseline: 1.2204x; 1.0962x over previous
//
#include <hip/hip_runtime.h>
#include <hip/hip_bf16.h>

// SimpleGATLayer fused kernel set for MI355X (gfx950).
// B=8, N=2048, F=U=128 (hard-coded from reference setup).
//
//  k_wt   : W(f,u) f32 -> WT(u,f) bf16          (tiny)
//  k_h    : H = X@W via MFMA -> HT(b,u,n) bf16, s(b,n), t(b,n) f32
//  k_attn : fused masked softmax(leaky(s_i+t_j)) @ H, relu, f32 out.
//           Round 10: A-stream folded INTO the loop (2xint4/lane/tile,
//           depth-2 register prefetch) with counted-vmcnt barriers so the
//           A loads stay in flight across them (T4 in its proper regime).
//           Deletes the serial self-pack phase; A-BW amortizes under the
//           stage/MFMA time. Loop fully unrolled (static aP indices).

#define NEG_INF -1.0e9f

typedef __bf16 bf16x8 __attribute__((ext_vector_type(8)));
typedef unsigned short ushort8 __attribute__((ext_vector_type(8)));
typedef float f32x4 __attribute__((ext_vector_type(4)));

__device__ __forceinline__ unsigned short f2b(float x) {
    // f32 -> bf16 round-to-nearest-even
    unsigned u = __builtin_bit_cast(unsigned, x);
    u += 0x7fffu + ((u >> 16) & 1u);
    return (unsigned short)(u >> 16);
}

__device__ __forceinline__ void gload_lds16(const void* g, void* l) {
    __builtin_amdgcn_global_load_lds(
        (const __attribute__((address_space(1))) void*)g,
        (__attribute__((address_space(3))) void*)l, 16, 0, 0);
}

// ---------------- K0: W transpose+convert ----------------
__global__ __launch_bounds__(256) void k_wt(const float* __restrict__ W,
                                            unsigned short* __restrict__ WT) {
    int tid = blockIdx.x * 256 + threadIdx.x;   // 16384 elements
    int u = tid >> 7, f = tid & 127;
    WT[tid] = f2b(W[f * 128 + u]);              // WT[u][f] = W[f][u]
}

// ---------------- K1: H = X@W, plus s,t and HT ----------------
// grid = 256 blocks x 256 thr; each wave computes 16 rows x 128 u.
__global__ __launch_bounds__(256) void k_h(const float* __restrict__ X,
                                           const unsigned short* __restrict__ WT,
                                           const float* __restrict__ a,
                                           unsigned short* __restrict__ HT,
                                           float* __restrict__ sbuf,
                                           float* __restrict__ tbuf) {
    const int tid  = threadIdx.x;
    const int w    = tid >> 6;
    const int lane = tid & 63;
    const int r    = lane & 15;     // MFMA row/col index
    const int cg   = lane >> 4;     // k-group 0..3
    const int row0 = blockIdx.x * 64 + w * 16;  // flattened (b*2048+n) row
    const int b    = row0 >> 11;
    const int n0   = row0 & 2047;
    const int arow = row0 + r;

    f32x4 acc[8] = {};

#pragma unroll
    for (int k0 = 0; k0 < 128; k0 += 32) {
        const float* xp = X + (size_t)arow * 128 + k0 + cg * 8;
        ushort8 xa;
#pragma unroll
        for (int j = 0; j < 8; j++) xa[j] = f2b(xp[j]);
        bf16x8 av = __builtin_bit_cast(bf16x8, xa);
#pragma unroll
        for (int ut = 0; ut < 8; ut++) {
            ushort8 wb = *(const ushort8*)(WT + (size_t)(ut * 16 + r) * 128 + k0 + cg * 8);
            acc[ut] = __builtin_amdgcn_mfma_f32_16x16x32_bf16(
                av, __builtin_bit_cast(bf16x8, wb), acc[ut], 0, 0, 0);
        }
    }

    // D layout: lane holds H[row0 + cg*4 + reg][ut*16 + r]
    float sp[4] = {0.f, 0.f, 0.f, 0.f};
    float tp[4] = {0.f, 0.f, 0.f, 0.f};
#pragma unroll
    for (int ut = 0; ut < 8; ut++) {
        int u = ut * 16 + r;
        float as = a[u];
        float ad = a[128 + u];
#pragma unroll
        for (int reg = 0; reg < 4; reg++) {
            float h = acc[ut][reg];
            int nrow = n0 + cg * 4 + reg;
            HT[((size_t)b * 128 + u) * 2048 + nrow] = f2b(h);
            sp[reg] += h * as;
            tp[reg] += h * ad;
        }
    }
#pragma unroll
    for (int msk = 1; msk < 16; msk <<= 1) {
#pragma unroll
        for (int reg = 0; reg < 4; reg++) {
            sp[reg] += __shfl_xor(sp[reg], msk);
            tp[reg] += __shfl_xor(tp[reg], msk);
        }
    }
    if (r == 0) {
#pragma unroll
        for (int reg = 0; reg < 4; reg++) {
            int row = row0 + cg * 4 + reg;
            sbuf[row] = sp[reg];
            tbuf[row] = tp[reg];
        }
    }
}

// ---------------- K2: fused masked-softmax attention @ H ----------------
// grid = 512 blocks (2/CU), block = 512 thr (8 waves).
// Block: 32 i-rows x 128 u of batch b = bid&7 (b-per-XCD locality).
// Wave w: i-subtile g=w&1 (16 rows), j-quarter jq=w>>1 (512 j, 16 tiles of 32).
// Per tile k: P computed from depth-2 prefetched A regs (2xint4/lane, the
// lane's own 8 adjacency ints) + t from LDS; HT tile staged via gload_lds
// dbuf. Counted vmcnt(6) at the barrier leaves next-tile A (2) + stage (4)
// in flight -> the 134 MB A-stream pipelines under stage/MFMA/barrier time.
__global__ __launch_bounds__(512, 4) void k_attn(const int* __restrict__ A,
                                                 const unsigned short* __restrict__ HT,
                                                 const float* __restrict__ sbuf,
                                                 const float* __restrict__ tbuf,
                                                 float* __restrict__ out) {
    __shared__ char smem[65536];        // stage: [jq][p][8KB]; reused for combine
    __shared__ float tS[2048];          // t row for this batch (8 KB)
    __shared__ float dSm[4][2][16];

    const int tid  = threadIdx.x;
    const int w    = tid >> 6;          // 0..7
    const int lane = tid & 63;
    const int r    = lane & 15;
    const int cg   = lane >> 4;
    const int g    = w & 1;             // i-subtile (16 rows)
    const int jq   = w >> 1;            // j-quarter (512 j)
    const int bid  = blockIdx.x;
    const int b    = bid & 7;           // batch pinned per XCD
    const int it   = bid >> 3;          // 0..63 i-tile
    const int i0   = it * 32;
    const int rot  = it & 15;           // per-block j-tile rotation

    const int irow = i0 + g * 16 + r;
    const float s_r = sbuf[b * 2048 + irow];
    const unsigned short* Hb = HT + ((size_t)b * 128) * 2048 + jq * 512;
    // this lane's adjacency slice base: row irow, quarter jq, k-group cg
    const int* Aq = A + ((size_t)(b * 2048 + irow)) * 2048 + jq * 512 + cg * 8;

    // staging geometry: wave stages 64 u-rows (4 instrs x 16 rows).
    // LDS tile = 128 rows x 64B (4 chunks of 16B); chunk hash both sides.
    const int srow = (lane >> 2);
    const int csrc = (lane & 3) ^ ((lane >> 2) & 3) ^ ((lane >> 4) & 3);
    char* const qbase = smem + jq * 16384;            // this quarter's 2 buffers
    const unsigned short* src0 = Hb + (size_t)(g * 64 + srow) * 2048 + csrc * 8;
    const int rsl = ((r & 3) ^ ((r >> 2) & 3));       // read-side hash base

    f32x4 acc[8] = {};
    float den = 0.f;

    // ---- stage t row once (512 thr x float4 = 2048 f32) ----
    *(float4*)(tS + tid * 4) = *(const float4*)(tbuf + b * 2048 + tid * 4);

    // ---- prologue: A tiles 0,1 into regs; HT tile 0 into LDS ----
    int4 aP[2][2];   // slot k&1; static indices (loop fully unrolled)
    {
        const int j0 = rot * 32;
        const int j1 = ((1 + rot) & 15) * 32;
        aP[0][0] = *(const int4*)(Aq + j0);
        aP[0][1] = *(const int4*)(Aq + j0 + 4);
        aP[1][0] = *(const int4*)(Aq + j1);
        aP[1][1] = *(const int4*)(Aq + j1 + 4);
#pragma unroll
        for (int i = 0; i < 4; i++)
            gload_lds16(src0 + (size_t)i * 16 * 2048 + j0,
                        qbase + (g * 4 + i) * 1024);
    }
    __syncthreads();   // full drain once: t + A(0,1) + stage0 ready

#pragma unroll
    for (int k = 0; k < 16; ++k) {
        const int p = k & 1;

        // ---- P fragment from prefetched A regs + t from LDS ----
        const float* tq = tS + jq * 512 + ((k + rot) & 15) * 32 + cg * 8;
        float4 t0 = *(const float4*)(tq);
        float4 t1 = *(const float4*)(tq + 4);
        float tv[8] = {t0.x, t0.y, t0.z, t0.w, t1.x, t1.y, t1.z, t1.w};
        int4 ca = aP[k & 1][0], cb = aP[k & 1][1];
        int ai[8] = {ca.x, ca.y, ca.z, ca.w, cb.x, cb.y, cb.z, cb.w};
        bf16x8 pa;
#pragma unroll
        for (int jj = 0; jj < 8; jj++) {
            float x = s_r + tv[jj];
            float e = fmaxf(x, 0.2f * x);          // leaky_relu
            float pp = __expf(e - 16.0f);          // fixed-scale softmax
            pp = ai[jj] > 0 ? pp : 0.f;            // mask
            den += pp;
            pa[jj] = (__bf16)pp;
        }

        // ---- refill A slot with tile k+2 (stays in flight across barrier) ----
        if (k < 14) {
            const int ja = ((k + 2 + rot) & 15) * 32;
            aP[k & 1][0] = *(const int4*)(Aq + ja);
            aP[k & 1][1] = *(const int4*)(Aq + ja + 4);
        }
        // ---- stage HT tile k+1 ----
        if (k < 15) {
            const int jn = ((k + 1 + rot) & 15) * 32;
            char* dst = qbase + (p ^ 1) * 8192;
#pragma unroll
            for (int i = 0; i < 4; i++)
                gload_lds16(src0 + (size_t)i * 16 * 2048 + jn * 1,
                            dst + (g * 4 + i) * 1024);
        }

        // T4 counted wait: drain stage(k); leave A(k+2)x2 + stage(k+1)x4.
        if (k < 14)      asm volatile("s_waitcnt vmcnt(6)" ::: "memory");
        else if (k < 15) asm volatile("s_waitcnt vmcnt(4)" ::: "memory");
        else             asm volatile("s_waitcnt vmcnt(0)" ::: "memory");
        __builtin_amdgcn_s_barrier();
        __builtin_amdgcn_sched_barrier(0);   // no ds_read hoisting (rule #18)

        // ---- B fragments from staged LDS tile + MFMA ----
        const char* buf = qbase + p * 8192;
#pragma unroll
        for (int ut = 0; ut < 8; ut++) {
            ushort8 hb = *(const ushort8*)(buf + (ut * 16 + r) * 64 +
                                           ((cg ^ rsl) * 16));
            acc[ut] = __builtin_amdgcn_mfma_f32_16x16x32_bf16(
                pa, __builtin_bit_cast(bf16x8, hb), acc[ut], 0, 0, 0);
        }

        __builtin_amdgcn_s_barrier();        // WAR guard on buffer flip
        __builtin_amdgcn_sched_barrier(0);
    }

    // per-wave denominator per row (sum over the 4 cg k-groups)
    den += __shfl_xor(den, 16);
    den += __shfl_xor(den, 32);

    // ---- combine the 4 j-quarters (reuse smem; padded stride 132 f32) ----
    float* accS = (float*)smem;
    if (cg == 0) dSm[jq][g][r] = den;     // lane r holds row r's partial
    if (jq != 0) {
        const int rowIdx = ((jq - 1) * 2 + g) * 16 + cg * 4;
#pragma unroll
        for (int ut = 0; ut < 8; ut++)
#pragma unroll
            for (int reg = 0; reg < 4; reg++)
                accS[(rowIdx + reg) * 132 + ut * 16 + r] = acc[ut][reg];
    }
    __syncthreads();
    if (jq == 0) {
        float dinv[4];
#pragma unroll
        for (int reg = 0; reg < 4; reg++) {
            const int row = cg * 4 + reg;
            dinv[reg] = 1.0f / (dSm[0][g][row] + dSm[1][g][row] +
                                dSm[2][g][row] + dSm[3][g][row]);
        }
#pragma unroll
        for (int ut = 0; ut < 8; ut++) {
#pragma unroll
            for (int reg = 0; reg < 4; reg++) {
                const int lrow = cg * 4 + reg;
                float num = acc[ut][reg]
                          + accS[((0 * 2 + g) * 16 + lrow) * 132 + ut * 16 + r]
                          + accS[((1 * 2 + g) * 16 + lrow) * 132 + ut * 16 + r]
                          + accS[((2 * 2 + g) * 16 + lrow) * 132 + ut * 16 + r];
                float o = fmaxf(num * dinv[reg], 0.f);
                out[((size_t)(b * 2048 + i0 + g * 16 + lrow)) * 128 +
                    ut * 16 + r] = o;
            }
        }
    }
}

extern "C" void kernel_launch(void* const* d_in, const int* in_sizes, int n_in,
                              void* d_out, int out_size, void* d_ws, size_t ws_size,
                              hipStream_t stream) {
    const float* X = (const float*)d_in[0];   // (8,2048,128) f32
    const int*   A = (const int*)d_in[1];     // (8,2048,2048) i32
    const float* W = (const float*)d_in[2];   // (128,128) f32
    const float* a = (const float*)d_in[3];   // (256,1) f32
    float* out = (float*)d_out;               // (8,2048,128) f32

    char* ws = (char*)d_ws;
    unsigned short* WT  = (unsigned short*)(ws);                  // 32 KB
    float*          sb  = (float*)(ws + 32768);                   // 64 KB
    float*          tb  = (float*)(ws + 98304);                   // 64 KB
    unsigned short* HT  = (unsigned short*)(ws + 163840);         // 4 MB

    k_wt<<<dim3(64), dim3(256), 0, stream>>>(W, WT);
    k_h<<<dim3(256), dim3(256), 0, stream>>>(X, WT, a, HT, sb, tb);
    k_attn<<<dim3(512), dim3(512), 0, stream>>>(A, HT, sb, tb, out);
}